// Round 3
// baseline (907.520 us; speedup 1.0000x reference)
//
#include <hip/hip_runtime.h>
#include <cstddef>
#include <cstdint>

#define S_TOK 8192
#define DDIM  2048
#define NEXP  64
#define CAPTY 128
#define KC    64
#define TPB   64                       // tokens per chunk
#define NBLK  (S_TOK / TPB)            // 128 chunks
#define SPLITK 8
#define KPER  (DDIM / SPLITK)          // 256
#define SEC   ((size_t)S_TOK * NEXP * CAPTY)   // 67,108,864
#define NGEMM (NBLK * SPLITK)          // 1024
#define NFILL 4096
#define NTOT  (NGEMM + NFILL)          // 5120

// LDS overlay: gemm staging tiles vs softmax probs (used after gemm phase)
struct GemmSm { float xs[KC][TPB + 2]; float ws2[KC][NEXP]; };   // 33,280 B
struct SoftSm { float probs[TPB][NEXP + 1]; int sexp[TPB]; };    // 16,896 B
union SMemU { GemmSm g; SoftSm s; };

// ---------------------------------------------------------------------------
// Fused kernel: interleaved roles. bid%5==0 -> split-K GEMM block (1024),
// else -> zero-fill block (4096). Last-arriving split-K block per token
// chunk also performs softmax/argmax/rank/hist for that chunk (hidden under
// the fill blocks' 537 MB of mandatory zero writes).
// ---------------------------------------------------------------------------
__global__ __launch_bounds__(256)
void fused_kernel(const float* __restrict__ x, const float* __restrict__ wg,
                  float* __restrict__ part, float* __restrict__ gate_s,
                  int* __restrict__ expert, int* __restrict__ rank,
                  int* __restrict__ hist, float* __restrict__ partial_g,
                  int* __restrict__ done, float* __restrict__ out)
{
    __shared__ SMemU sm;
    __shared__ int s_old;
    const int tid = threadIdx.x;
    const int bid = blockIdx.x;

    if (bid % 5 != 0) {
        // ------------------- fill path: zero 2*SEC floats -------------------
        const size_t fidx = (size_t)(bid - bid / 5 - 1);       // 0..4095
        const size_t n4 = (size_t)2 * SEC / 4;                 // 33,554,432 float4
        float4* out4 = (float4*)out;
        size_t i = fidx * 256 + tid;
        const size_t stride = (size_t)NFILL * 256;
        float4 z = make_float4(0.f, 0.f, 0.f, 0.f);
        for (size_t idx = i; idx < n4; idx += stride) out4[idx] = z;
        if (i == 0) out[2 * SEC] = 0.0f;                       // last element
        return;
    }

    // ------------------- gemm path -------------------
    const int g  = bid / 5;                 // 0..1023
    const int kp = g & (SPLITK - 1);
    const int tc = g >> 3;
    const int t_base = tc * TPB;
    const int k_base = kp * KPER;
    const int e4 = tid & 15;                // experts 4*e4..+3
    const int tg = tid >> 4;                // tokens  4*tg..+3

    float acc[4][4];
#pragma unroll
    for (int i = 0; i < 4; ++i)
#pragma unroll
        for (int j = 0; j < 4; ++j) acc[i][j] = 0.0f;

    for (int kc0 = 0; kc0 < KPER; kc0 += KC) {
        const int kc = k_base + kc0;
        __syncthreads();
#pragma unroll
        for (int m = 0; m < 4; ++m) {
            int idx = tid + 256 * m;        // 0..1023
            int t = idx & 63;
            int c = idx >> 6;               // float4 column 0..15
            float4 v = *(const float4*)(x + (size_t)(t_base + t) * DDIM + kc + c * 4);
            sm.g.xs[c * 4 + 0][t] = v.x;
            sm.g.xs[c * 4 + 1][t] = v.y;
            sm.g.xs[c * 4 + 2][t] = v.z;
            sm.g.xs[c * 4 + 3][t] = v.w;
            float4 w = *(const float4*)(wg + (size_t)t * DDIM + kc + c * 4);
            sm.g.ws2[c * 4 + 0][t] = w.x;
            sm.g.ws2[c * 4 + 1][t] = w.y;
            sm.g.ws2[c * 4 + 2][t] = w.z;
            sm.g.ws2[c * 4 + 3][t] = w.w;
        }
        __syncthreads();
#pragma unroll 8
        for (int k = 0; k < KC; ++k) {
            float4 wv = *(const float4*)&sm.g.ws2[k][e4 * 4];
            float2 xa = *(const float2*)&sm.g.xs[k][tg * 4];
            float2 xb = *(const float2*)&sm.g.xs[k][tg * 4 + 2];
            float xv0 = xa.x, xv1 = xa.y, xv2 = xb.x, xv3 = xb.y;
            acc[0][0] += xv0 * wv.x; acc[0][1] += xv0 * wv.y;
            acc[0][2] += xv0 * wv.z; acc[0][3] += xv0 * wv.w;
            acc[1][0] += xv1 * wv.x; acc[1][1] += xv1 * wv.y;
            acc[1][2] += xv1 * wv.z; acc[1][3] += xv1 * wv.w;
            acc[2][0] += xv2 * wv.x; acc[2][1] += xv2 * wv.y;
            acc[2][2] += xv2 * wv.z; acc[2][3] += xv2 * wv.w;
            acc[3][0] += xv3 * wv.x; acc[3][1] += xv3 * wv.y;
            acc[3][2] += xv3 * wv.z; acc[3][3] += xv3 * wv.w;
        }
    }

#pragma unroll
    for (int i = 0; i < 4; ++i) {
        float4 v = make_float4(acc[i][0], acc[i][1], acc[i][2], acc[i][3]);
        *(float4*)(part + ((size_t)kp * S_TOK + t_base + tg * 4 + i) * NEXP + e4 * 4) = v;
    }

    // release partials, count arrivals for this token chunk
    __threadfence();
    __syncthreads();
    if (tid == 0) s_old = atomicAdd(&done[tc], 1);
    __syncthreads();
    if (s_old != SPLITK - 1) return;        // not the last split-K arrival
    __threadfence();                        // acquire: make all parts visible

    // ---------- softmax/argmax/rank/hist for chunk tc (this block only) ----
    {
        const int t = tid >> 2, q = tid & 3;    // 4 threads per token
        const int tok = t_base + t;
#pragma unroll
        for (int jj = 0; jj < 4; ++jj) {
            float4 a = make_float4(0.f, 0.f, 0.f, 0.f);
#pragma unroll
            for (int kpp = 0; kpp < SPLITK; ++kpp) {
                float4 v = *(const float4*)(part + ((size_t)kpp * S_TOK + tok) * NEXP + q * 16 + jj * 4);
                a.x += v.x; a.y += v.y; a.z += v.z; a.w += v.w;
            }
            sm.s.probs[t][q * 16 + jj * 4 + 0] = a.x;
            sm.s.probs[t][q * 16 + jj * 4 + 1] = a.y;
            sm.s.probs[t][q * 16 + jj * 4 + 2] = a.z;
            sm.s.probs[t][q * 16 + jj * 4 + 3] = a.w;
        }
        __syncthreads();

        if (tid < TPB) {                    // one thread per token
            const int t2 = tid, tok2 = t_base + t2;
            float m = -1e30f; int am = 0;
            for (int e = 0; e < NEXP; ++e) {
                float v = sm.s.probs[t2][e];
                if (v > m) { m = v; am = e; }       // strict > = np.argmax
            }
            float s = 0.0f;
            for (int e = 0; e < NEXP; ++e) s += __expf(sm.s.probs[t2][e] - m);
            float rcp = 1.0f / s;                   // top-1 gate value
            for (int e = 0; e < NEXP; ++e)
                sm.s.probs[t2][e] = __expf(sm.s.probs[t2][e] - m) * rcp;
            sm.s.sexp[t2] = am;
            gate_s[tok2] = rcp;
            expert[tok2] = am;
        }
        __syncthreads();

        if (tid < TPB) {                    // rank within chunk (token order)
            const int t2 = tid;
            const int am = sm.s.sexp[t2];
            int r = 0;
            for (int u = 0; u < t2; ++u) r += (sm.s.sexp[u] == am) ? 1 : 0;
            rank[t_base + t2] = r;
        } else if (tid < 2 * TPB) {         // per-expert histogram + gate sums
            const int e = tid - TPB;
            float pg = 0.0f; int cnt = 0;
            for (int u = 0; u < TPB; ++u) {
                pg  += sm.s.probs[u][e];
                cnt += (sm.s.sexp[u] == e) ? 1 : 0;
            }
            partial_g[tc * NEXP + e] = pg;
            hist[tc * NEXP + e]      = cnt;
        }
    }
}

// ---------------------------------------------------------------------------
// Kernel 2: per-expert exclusive scan over 128 chunks + l_aux + scatter.
// Single block of 256 threads; kernel boundary orders it after all fills.
// ---------------------------------------------------------------------------
__global__ __launch_bounds__(256)
void scan_scatter_kernel(const int* __restrict__ hist, const float* __restrict__ partial_g,
                         const float* __restrict__ gate_s, const int* __restrict__ expert,
                         const int* __restrict__ rank, float* __restrict__ out)
{
    __shared__ int base_s[NBLK][NEXP];      // 32 KB
    const int tid = threadIdx.x;

    if (tid < NEXP) {                       // wave 0: serial scan per expert
        const int e = tid;
        int base = 0; float sg = 0.0f;
        for (int c = 0; c < NBLK; ++c) {
            base_s[c][e] = base;
            base += hist[c * NEXP + e];
            sg  += partial_g[c * NEXP + e];
        }
        float v = sg * (float)base;         // sum_gates[e] * pre-drop count[e]
#pragma unroll
        for (int off = 32; off > 0; off >>= 1) v += __shfl_down(v, off);
        if (e == 0) out[0] = v * (64.0f / (8192.0f * 8192.0f));   // l_aux
    }
    __syncthreads();

    for (int s = tid; s < S_TOK; s += 256) {
        const int e = expert[s];
        const int loc = base_s[s >> 6][e] + rank[s];
        if (loc < CAPTY) {
            size_t idx = 1 + (size_t)s * (NEXP * CAPTY) + (size_t)e * CAPTY + loc;
            out[idx]       = gate_s[s];     // combine1_sec
            out[idx + SEC] = 1.0f;          // dispatch_mask
        }
    }
}

extern "C" void kernel_launch(void* const* d_in, const int* in_sizes, int n_in,
                              void* d_out, int out_size, void* d_ws, size_t ws_size,
                              hipStream_t stream)
{
    const float* x  = (const float*)d_in[0];
    const float* wg = (const float*)d_in[1];
    float* out = (float*)d_out;
    char* ws = (char*)d_ws;

    float* part      = (float*)(ws + 0);                       // 16 MB
    size_t off = (size_t)SPLITK * S_TOK * NEXP * sizeof(float);
    float* gate_s    = (float*)(ws + off);          off += 32768;
    int*   expert    = (int*)  (ws + off);          off += 32768;
    int*   rank      = (int*)  (ws + off);          off += 32768;
    int*   hist      = (int*)  (ws + off);          off += 32768;
    float* partial_g = (float*)(ws + off);          off += 32768;
    int*   done      = (int*)  (ws + off);                     // 128 ints

    // ws is poisoned 0xAA before every launch: zero the arrival counters
    hipMemsetAsync(done, 0, NBLK * sizeof(int), stream);

    fused_kernel<<<NTOT, 256, 0, stream>>>(x, wg, part, gate_s, expert, rank,
                                           hist, partial_g, done, out);
    scan_scatter_kernel<<<1, 256, 0, stream>>>(hist, partial_g, gate_s, expert, rank, out);
}